// Round 1
// baseline (478.834 us; speedup 1.0000x reference)
//
#include <hip/hip_runtime.h>

typedef float v2f __attribute__((ext_vector_type(2)));

#define T_LEN 512
#define INP 5
#define HID 32

__device__ __forceinline__ v2f pkfma(v2f a, v2f b, v2f c) {
    return __builtin_elementwise_fma(a, b, c);
}

__global__ __launch_bounds__(64, 2) void lstm2_fused(
    const float* __restrict__ x,
    const float* __restrict__ Wih0, const float* __restrict__ Whh0,
    const float* __restrict__ bih0, const float* __restrict__ bhh0,
    const float* __restrict__ Wih1, const float* __restrict__ Whh1,
    const float* __restrict__ bih1, const float* __restrict__ bhh1,
    const float* __restrict__ Wfc,  const float* __restrict__ bfc,
    float* __restrict__ out)
{
    const int b = blockIdx.x;
    const int l = threadIdx.x;        // 0..63
    const int glo = l, ghi = l + 64;  // this lane's two gate rows
    const bool isIG = (l < 32);       // lanes<32: (i,g); lanes>=32: (f,o)
    const int m = l & 31;             // hidden index this lane updates

    __shared__ __align__(16) float h0s[HID];
    __shared__ __align__(16) float h1s[HID];

    // ---- preload weights, packed over j-pairs: w[j2] = (W[g][2*j2], W[g][2*j2+1]) ----
    v2f whh0_lo[16], whh0_hi[16], wih1_lo[16], wih1_hi[16], whh1_lo[16], whh1_hi[16];

#define LOADW(dst_lo, dst_hi, W) { \
    const float4* rlo_ = (const float4*)((W) + glo * HID); \
    const float4* rhi_ = (const float4*)((W) + ghi * HID); \
    _Pragma("unroll") \
    for (int r = 0; r < 8; ++r) { \
        float4 a_ = rlo_[r], c_ = rhi_[r]; \
        dst_lo[2*r]   = (v2f){a_.x, a_.y}; \
        dst_lo[2*r+1] = (v2f){a_.z, a_.w}; \
        dst_hi[2*r]   = (v2f){c_.x, c_.y}; \
        dst_hi[2*r+1] = (v2f){c_.z, c_.w}; \
    } }

    LOADW(whh0_lo, whh0_hi, Whh0)
    LOADW(wih1_lo, wih1_hi, Wih1)
    LOADW(whh1_lo, whh1_hi, Whh1)
#undef LOADW

    float wx_lo[INP], wx_hi[INP];
    #pragma unroll
    for (int d = 0; d < INP; ++d) {
        wx_lo[d] = Wih0[glo * INP + d];
        wx_hi[d] = Wih0[ghi * INP + d];
    }

    const float bias0_lo = bih0[glo] + bhh0[glo];
    const float bias0_hi = bih0[ghi] + bhh0[ghi];
    const float bias1_lo = bih1[glo] + bhh1[glo];
    const float bias1_hi = bih1[ghi] + bhh1[ghi];

    // branch-free activation constants: act(v) = sc*rcp(1+exp(kk*v)) + bb
    // lo gate is always sigmoid (i or f). hi gate: tanh (g) on lanes<32, sigmoid (o) on lanes>=32.
    const float kk_hi = isIG ? -2.0f : -1.0f;
    const float sc_hi = isIG ?  2.0f :  1.0f;
    const float bb_hi = isIG ? -1.0f :  0.0f;

    float c0 = 0.0f, c1 = 0.0f;
    float h1last = 0.0f;
    if (l < HID) { h0s[l] = 0.0f; h1s[l] = 0.0f; }
    __syncthreads();

    const float* xb = x + (size_t)b * T_LEN * INP;

    for (int t = 0; t < T_LEN; ++t) {
        const float* xp = xb + t * INP;
        const float x0 = xp[0], x1 = xp[1], x2 = xp[2], x3 = xp[3], x4 = xp[4];

        const float4* h04 = (const float4*)h0s;
        const float4* h14 = (const float4*)h1s;

        // ================= layer 0 =================
        v2f aL0 = (v2f)0.0f, aL1 = (v2f)0.0f, aH0 = (v2f)0.0f, aH1 = (v2f)0.0f;
        #pragma unroll
        for (int r = 0; r < 8; ++r) {
            float4 hq = h04[r];                 // uniform-address b128: LDS broadcast
            v2f hp0 = (v2f){hq.x, hq.y};
            v2f hp1 = (v2f){hq.z, hq.w};
            aL0 = pkfma(whh0_lo[2*r],   hp0, aL0);
            aL1 = pkfma(whh0_lo[2*r+1], hp1, aL1);
            aH0 = pkfma(whh0_hi[2*r],   hp0, aH0);
            aH1 = pkfma(whh0_hi[2*r+1], hp1, aH1);
        }
        float gl = bias0_lo + ((aL0.x + aL1.x) + (aL0.y + aL1.y));
        float gh = bias0_hi + ((aH0.x + aH1.x) + (aH0.y + aH1.y));
        gl = fmaf(wx_lo[0], x0, gl); gl = fmaf(wx_lo[1], x1, gl);
        gl = fmaf(wx_lo[2], x2, gl); gl = fmaf(wx_lo[3], x3, gl);
        gl = fmaf(wx_lo[4], x4, gl);
        gh = fmaf(wx_hi[0], x0, gh); gh = fmaf(wx_hi[1], x1, gh);
        gh = fmaf(wx_hi[2], x2, gh); gh = fmaf(wx_hi[3], x3, gh);
        gh = fmaf(wx_hi[4], x4, gh);

        float actL = __builtin_amdgcn_rcpf(1.0f + __expf(-gl));                     // sigmoid
        float actH = fmaf(sc_hi, __builtin_amdgcn_rcpf(1.0f + __expf(kk_hi * gh)), bb_hi);
        float actLs = __shfl_xor(actL, 32);
        float actHs = __shfl_xor(actH, 32);
        float i_ = isIG ? actL  : actLs;
        float f_ = isIG ? actLs : actL;
        float g_ = isIG ? actH  : actHs;
        float o_ = isIG ? actHs : actH;
        c0 = fmaf(f_, c0, i_ * g_);
        float th0 = fmaf(2.0f, __builtin_amdgcn_rcpf(1.0f + __expf(-2.0f * c0)), -1.0f);
        float h0new = o_ * th0;
        if (l < HID) h0s[l] = h0new;
        __syncthreads();

        // ================= layer 1 =================
        v2f bL0 = (v2f)0.0f, bL1 = (v2f)0.0f, bH0 = (v2f)0.0f, bH1 = (v2f)0.0f;
        #pragma unroll
        for (int r = 0; r < 8; ++r) {
            float4 hq = h04[r];                 // h0 (fresh, post-barrier)
            v2f hp0 = (v2f){hq.x, hq.y};
            v2f hp1 = (v2f){hq.z, hq.w};
            bL0 = pkfma(wih1_lo[2*r],   hp0, bL0);
            bL1 = pkfma(wih1_lo[2*r+1], hp1, bL1);
            bH0 = pkfma(wih1_hi[2*r],   hp0, bH0);
            bH1 = pkfma(wih1_hi[2*r+1], hp1, bH1);
        }
        #pragma unroll
        for (int r = 0; r < 8; ++r) {
            float4 hq = h14[r];                 // h1 (previous timestep)
            v2f hp0 = (v2f){hq.x, hq.y};
            v2f hp1 = (v2f){hq.z, hq.w};
            bL0 = pkfma(whh1_lo[2*r],   hp0, bL0);
            bL1 = pkfma(whh1_lo[2*r+1], hp1, bL1);
            bH0 = pkfma(whh1_hi[2*r],   hp0, bH0);
            bH1 = pkfma(whh1_hi[2*r+1], hp1, bH1);
        }
        float gl1 = bias1_lo + ((bL0.x + bL1.x) + (bL0.y + bL1.y));
        float gh1 = bias1_hi + ((bH0.x + bH1.x) + (bH0.y + bH1.y));

        float actL1 = __builtin_amdgcn_rcpf(1.0f + __expf(-gl1));
        float actH1 = fmaf(sc_hi, __builtin_amdgcn_rcpf(1.0f + __expf(kk_hi * gh1)), bb_hi);
        float actL1s = __shfl_xor(actL1, 32);
        float actH1s = __shfl_xor(actH1, 32);
        float i1 = isIG ? actL1  : actL1s;
        float f1 = isIG ? actL1s : actL1;
        float g1 = isIG ? actH1  : actH1s;
        float o1 = isIG ? actH1s : actH1;
        c1 = fmaf(f1, c1, i1 * g1);
        float th1 = fmaf(2.0f, __builtin_amdgcn_rcpf(1.0f + __expf(-2.0f * c1)), -1.0f);
        h1last = o1 * th1;
        if (l < HID) h1s[l] = h1last;
        __syncthreads();
    }

    // ---- final linear head: out[b][o] = sum_j Wfc[o][j]*h1[j] + bfc[o] ----
    float p0 = isIG ? (Wfc[m]       * h1last) : 0.0f;
    float p1 = isIG ? (Wfc[HID + m] * h1last) : 0.0f;
    #pragma unroll
    for (int off = 32; off >= 1; off >>= 1) {
        p0 += __shfl_xor(p0, off);
        p1 += __shfl_xor(p1, off);
    }
    if (l == 0) {
        out[2 * b + 0] = p0 + bfc[0];
        out[2 * b + 1] = p1 + bfc[1];
    }
}

extern "C" void kernel_launch(void* const* d_in, const int* in_sizes, int n_in,
                              void* d_out, int out_size, void* d_ws, size_t ws_size,
                              hipStream_t stream) {
    const float* x    = (const float*)d_in[0];
    const float* Wih0 = (const float*)d_in[1];
    const float* Whh0 = (const float*)d_in[2];
    const float* bih0 = (const float*)d_in[3];
    const float* bhh0 = (const float*)d_in[4];
    const float* Wih1 = (const float*)d_in[5];
    const float* Whh1 = (const float*)d_in[6];
    const float* bih1 = (const float*)d_in[7];
    const float* bhh1 = (const float*)d_in[8];
    const float* Wfc  = (const float*)d_in[9];
    const float* bfc  = (const float*)d_in[10];
    float* out = (float*)d_out;

    const int nb = in_sizes[0] / (T_LEN * INP);   // = 2048 batch elements
    lstm2_fused<<<dim3(nb), dim3(64), 0, stream>>>(
        x, Wih0, Whh0, bih0, bhh0, Wih1, Whh1, bih1, bhh1, Wfc, bfc, out);
}